// Round 1
// baseline (223.798 us; speedup 1.0000x reference)
//
#include <hip/hip_runtime.h>
#include <hip/hip_bf16.h>

// x: [B=64, N=4096, D=128] fp32; R: [B, N, 2, 2] fp32
// y[b,n,2c+i] = sum_j R[b,n,i,j] * x[b,n,2c+j]
// One thread handles one float4 of x (= two 2-vectors). 32 float4 per point.

__global__ __launch_bounds__(256) void rotate2d_kernel(
    const float4* __restrict__ x,
    const float4* __restrict__ R,   // one float4 per point: (R00,R01,R10,R11)
    float4* __restrict__ out,
    int n4)                         // total float4 elements of x
{
    int t = blockIdx.x * blockDim.x + threadIdx.x;
    if (t >= n4) return;

    float4 xv = x[t];
    float4 r  = R[t >> 5];          // 128 floats / 4 = 32 float4 per (b,n) point

    float4 y;
    y.x = r.x * xv.x + r.y * xv.y;  // R00*x0 + R01*x1
    y.y = r.z * xv.x + r.w * xv.y;  // R10*x0 + R11*x1
    y.z = r.x * xv.z + r.y * xv.w;  // R00*x2 + R01*x3
    y.w = r.z * xv.z + r.w * xv.w;  // R10*x2 + R11*x3

    out[t] = y;
}

extern "C" void kernel_launch(void* const* d_in, const int* in_sizes, int n_in,
                              void* d_out, int out_size, void* d_ws, size_t ws_size,
                              hipStream_t stream) {
    const float4* x = (const float4*)d_in[0];
    const float4* R = (const float4*)d_in[1];
    float4* out = (float4*)d_out;

    int n4 = in_sizes[0] / 4;       // 64*4096*128 / 4 = 8,388,608
    int block = 256;
    int grid = (n4 + block - 1) / block;

    rotate2d_kernel<<<grid, block, 0, stream>>>(x, R, out, n4);
}

// Round 3
// 222.516 us; speedup vs baseline: 1.0058x; 1.0058x over previous
//
#include <hip/hip_runtime.h>
#include <hip/hip_bf16.h>

// x: [B=64, N=4096, D=128] fp32; R: [B, N, 2, 2] fp32
// y[b,n,2c+i] = sum_j R[b,n,i,j] * x[b,n,2c+j]
// Grid-stride loop, one float4 of x (= two 2-vectors) per iteration.
// x/out streamed with nontemporal hints (zero reuse); R stays cached
// (each point's 16B of R is consumed by 32 consecutive threads).

typedef float f32x4 __attribute__((ext_vector_type(4)));

__global__ __launch_bounds__(256) void rotate2d_kernel(
    const f32x4* __restrict__ x,
    const f32x4* __restrict__ R,    // one f32x4 per point: (R00,R01,R10,R11)
    f32x4* __restrict__ out,
    int n4)                         // total f32x4 elements of x
{
    int stride = blockDim.x * gridDim.x;
    for (int t = blockIdx.x * blockDim.x + threadIdx.x; t < n4; t += stride) {
        f32x4 xv = __builtin_nontemporal_load(&x[t]);
        f32x4 r  = R[t >> 5];       // 128 floats / 4 = 32 f32x4 per (b,n) point

        f32x4 y;
        y.x = r.x * xv.x + r.y * xv.y;  // R00*x0 + R01*x1
        y.y = r.z * xv.x + r.w * xv.y;  // R10*x0 + R11*x1
        y.z = r.x * xv.z + r.y * xv.w;  // R00*x2 + R01*x3
        y.w = r.z * xv.z + r.w * xv.w;  // R10*x2 + R11*x3

        __builtin_nontemporal_store(y, &out[t]);
    }
}

extern "C" void kernel_launch(void* const* d_in, const int* in_sizes, int n_in,
                              void* d_out, int out_size, void* d_ws, size_t ws_size,
                              hipStream_t stream) {
    const f32x4* x = (const f32x4*)d_in[0];
    const f32x4* R = (const f32x4*)d_in[1];
    f32x4* out = (f32x4*)d_out;

    int n4 = in_sizes[0] / 4;       // 64*4096*128 / 4 = 8,388,608
    int block = 256;
    // Grid-stride: 8192 blocks * 256 threads * 4 iters = 8.4M f32x4.
    int grid = 8192;

    rotate2d_kernel<<<grid, block, 0, stream>>>(x, R, out, n4);
}